// Round 1
// baseline (890.007 us; speedup 1.0000x reference)
//
#include <hip/hip_runtime.h>
#include <hip/hip_bf16.h>
#include <math.h>

// ---------------- degree / norm ----------------

__global__ void k_fill1(float* __restrict__ deg, int n) {
    int i = blockIdx.x * blockDim.x + threadIdx.x;
    if (i < n) deg[i] = 1.0f;  // self-loop contributes 1 to in-degree
}

__global__ void k_count(const int* __restrict__ dst, float* __restrict__ deg, int e) {
    int i = blockIdx.x * blockDim.x + threadIdx.x;
    if (i < e) atomicAdd(&deg[dst[i]], 1.0f);
}

__global__ void k_rsqrt(float* __restrict__ deg, int n) {
    int i = blockIdx.x * blockDim.x + threadIdx.x;
    if (i < n) deg[i] = rsqrtf(deg[i]);  // deg >= 1 always (self-loop)
}

// ---------------- aggregation (scatter-add with symmetric norm) ----------------

// init agg with self-loop term: agg[i][f] = feat[i][f] * dinv[i]^2
template<int D>
__global__ void k_selfloop(const float* __restrict__ feat, const float* __restrict__ dinv,
                           float* __restrict__ agg, int n) {
    int t = blockIdx.x * blockDim.x + threadIdx.x;
    if (t >= n * D) return;
    int i = t / D;
    float dv = dinv[i];
    agg[t] = feat[t] * dv * dv;
}

// one thread per (edge, feature): agg[dst][f] += feat[src][f] * dinv[src]*dinv[dst]
template<int D, int LOG2D>
__global__ void k_edge(const int* __restrict__ src, const int* __restrict__ dst,
                       const float* __restrict__ feat, const float* __restrict__ dinv,
                       float* __restrict__ agg, int total) {
    int t = blockIdx.x * blockDim.x + threadIdx.x;
    if (t >= total) return;
    int e = t >> LOG2D;
    int f = t & (D - 1);
    int s = src[e];
    int d = dst[e];
    float nrm = dinv[s] * dinv[d];
    atomicAdd(&agg[(size_t)d * D + f], feat[(size_t)s * D + f] * nrm);
}

// ---------------- dense layers ----------------

// out[i][0..OUT) = act(agg[i][0..IN) @ W + b) ; W is [IN][OUT] row-major
template<int IN, int OUT, bool RELU>
__global__ void __launch_bounds__(256) k_dense(const float* __restrict__ agg,
                                               const float* __restrict__ W,
                                               const float* __restrict__ b,
                                               float* __restrict__ out, int n) {
    __shared__ float sW[IN * OUT];
    __shared__ float sb[OUT];
    for (int i = threadIdx.x; i < IN * OUT; i += blockDim.x) sW[i] = W[i];
    for (int i = threadIdx.x; i < OUT; i += blockDim.x) sb[i] = b[i];
    __syncthreads();
    int node = blockIdx.x * blockDim.x + threadIdx.x;
    if (node >= n) return;
    float in[IN];
#pragma unroll
    for (int k = 0; k < IN; k++) in[k] = agg[(size_t)node * IN + k];
#pragma unroll
    for (int j = 0; j < OUT; j++) {
        float acc = sb[j];
#pragma unroll
        for (int k = 0; k < IN; k++) acc += in[k] * sW[k * OUT + j];
        out[(size_t)node * OUT + j] = RELU ? fmaxf(acc, 0.0f) : acc;
    }
}

// t[i] = dot(h[i][0..64), W3[0..64))   (no bias; bias added after aggregation)
__global__ void __launch_bounds__(256) k_dot64(const float* __restrict__ h,
                                               const float* __restrict__ W,
                                               float* __restrict__ out, int n) {
    __shared__ float sW[64];
    if (threadIdx.x < 64) sW[threadIdx.x] = W[threadIdx.x];
    __syncthreads();
    int i = blockIdx.x * blockDim.x + threadIdx.x;
    if (i >= n) return;
    const float4* row = (const float4*)(h + (size_t)i * 64);
    float acc = 0.0f;
#pragma unroll
    for (int k = 0; k < 16; k++) {
        float4 v = row[k];
        acc += v.x * sW[4 * k + 0] + v.y * sW[4 * k + 1] + v.z * sW[4 * k + 2] + v.w * sW[4 * k + 3];
    }
    out[i] = acc;
}

__global__ void k_sigmoid(const float* __restrict__ agg, const float* __restrict__ b3,
                          float* __restrict__ out, int n) {
    int i = blockIdx.x * blockDim.x + threadIdx.x;
    if (i < n) {
        float v = agg[i] + b3[0];
        out[i] = 1.0f / (1.0f + expf(-v));
    }
}

// ---------------- launch ----------------

static inline int cdiv(int a, int b) { return (a + b - 1) / b; }

extern "C" void kernel_launch(void* const* d_in, const int* in_sizes, int n_in,
                              void* d_out, int out_size, void* d_ws, size_t ws_size,
                              hipStream_t stream) {
    const float* x  = (const float*)d_in[0];
    const int*   ei = (const int*)d_in[1];
    const float* W1 = (const float*)d_in[2];
    const float* b1 = (const float*)d_in[3];
    const float* W2 = (const float*)d_in[4];
    const float* b2 = (const float*)d_in[5];
    const float* W3 = (const float*)d_in[6];
    const float* b3 = (const float*)d_in[7];

    const int n = in_sizes[0] / 16;
    const int e = in_sizes[1] / 2;
    const int* src = ei;
    const int* dst = ei + e;

    // workspace layout (floats): dinv [n] | bufA [32n] | bufB [64n]
    float* dinv = (float*)d_ws;
    float* bufA = dinv + n;
    float* bufB = bufA + (size_t)32 * n;

    float* out = (float*)d_out;

    const int B = 256;

    // degree -> dinv (in place)
    k_fill1<<<cdiv(n, B), B, 0, stream>>>(dinv, n);
    k_count<<<cdiv(e, B), B, 0, stream>>>(dst, dinv, e);
    k_rsqrt<<<cdiv(n, B), B, 0, stream>>>(dinv, n);

    // ---- Layer 1: agg0 = A_hat @ x (16-dim), h1 = relu(agg0 @ W1 + b1) (32-dim)
    k_selfloop<16><<<cdiv(n * 16, B), B, 0, stream>>>(x, dinv, bufA, n);
    k_edge<16, 4><<<cdiv(e * 16, B), B, 0, stream>>>(src, dst, x, dinv, bufA, e * 16);
    k_dense<16, 32, true><<<cdiv(n, B), B, 0, stream>>>(bufA, W1, b1, bufB, n);  // h1 -> bufB

    // ---- Layer 2: agg1 = A_hat @ h1 (32-dim), h2 = relu(agg1 @ W2 + b2) (64-dim)
    k_selfloop<32><<<cdiv(n * 32, B), B, 0, stream>>>(bufB, dinv, bufA, n);
    k_edge<32, 5><<<cdiv(e * 32, B), B, 0, stream>>>(src, dst, bufB, dinv, bufA, e * 32);
    k_dense<32, 64, true><<<cdiv(n, B), B, 0, stream>>>(bufA, W2, b2, bufB, n);  // h2 -> bufB

    // ---- Layer 3: t = h2 @ W3 (1-dim), agg2 = A_hat @ t, out = sigmoid(agg2 + b3)
    k_dot64<<<cdiv(n, B), B, 0, stream>>>(bufB, W3, bufA, n);                    // t -> bufA
    k_selfloop<1><<<cdiv(n, B), B, 0, stream>>>(bufA, dinv, bufB, n);            // agg2 -> bufB
    k_edge<1, 0><<<cdiv(e, B), B, 0, stream>>>(src, dst, bufA, dinv, bufB, e);
    k_sigmoid<<<cdiv(n, B), B, 0, stream>>>(bufB, b3, out, n);
}

// Round 2
// 644.099 us; speedup vs baseline: 1.3818x; 1.3818x over previous
//
#include <hip/hip_runtime.h>
#include <hip/hip_bf16.h>
#include <math.h>

// ---------------- CSR build: histogram, scan, scatter ----------------

__global__ void k_hist(const int* __restrict__ dst, int* __restrict__ cnt, int e) {
    int i = blockIdx.x * blockDim.x + threadIdx.x;
    if (i < e) atomicAdd(&cnt[dst[i]], 1);
}

__global__ void k_dinv(const int* __restrict__ cnt, float* __restrict__ dinv, int n) {
    int i = blockIdx.x * blockDim.x + threadIdx.x;
    if (i < n) dinv[i] = rsqrtf((float)cnt[i] + 1.0f);  // +1 self-loop
}

#define SB 512

__global__ void __launch_bounds__(SB) k_scan1(const int* __restrict__ cnt, int* __restrict__ partial, int n) {
    __shared__ int sh[SB];
    int i = blockIdx.x * SB + threadIdx.x;
    sh[threadIdx.x] = (i < n) ? cnt[i] : 0;
    __syncthreads();
    for (int s = SB / 2; s > 0; s >>= 1) {
        if (threadIdx.x < s) sh[threadIdx.x] += sh[threadIdx.x + s];
        __syncthreads();
    }
    if (threadIdx.x == 0) partial[blockIdx.x] = sh[0];
}

// single block, exclusive-scan up to 1024 partials
__global__ void __launch_bounds__(1024) k_scanp(int* __restrict__ partial, int G) {
    __shared__ int sh[1024];
    int t = threadIdx.x;
    int v = (t < G) ? partial[t] : 0;
    sh[t] = v;
    __syncthreads();
    for (int o = 1; o < 1024; o <<= 1) {
        int u = (t >= o) ? sh[t - o] : 0;
        __syncthreads();
        sh[t] += u;
        __syncthreads();
    }
    if (t < G) partial[t] = sh[t] - v;  // exclusive
}

__global__ void __launch_bounds__(SB) k_scan2(const int* __restrict__ cnt, const int* __restrict__ partial,
                                              int* __restrict__ rowstart, int* __restrict__ cursor,
                                              int n, int e) {
    __shared__ int sh[SB];
    int i = blockIdx.x * SB + threadIdx.x;
    int v = (i < n) ? cnt[i] : 0;
    sh[threadIdx.x] = v;
    __syncthreads();
    for (int o = 1; o < SB; o <<= 1) {
        int u = (threadIdx.x >= o) ? sh[threadIdx.x - o] : 0;
        __syncthreads();
        sh[threadIdx.x] += u;
        __syncthreads();
    }
    if (i < n) {
        int ex = sh[threadIdx.x] - v + partial[blockIdx.x];
        rowstart[i] = ex;
        cursor[i] = ex;
    }
    if (i == 0) rowstart[n] = e;
}

__global__ void k_scatter(const int* __restrict__ src, const int* __restrict__ dst,
                          int* __restrict__ cursor, int* __restrict__ csr_src, int e) {
    int i = blockIdx.x * blockDim.x + threadIdx.x;
    if (i < e) {
        int d = dst[i];
        int slot = atomicAdd(&cursor[d], 1);
        csr_src[slot] = src[i];
    }
}

// ---------------- pull aggregation (no atomics) ----------------

// one wave per node; D/4 float4-lanes per edge slot, 64/(D/4) edge slots in flight.
// out[i] = dinv[i] * sum_{s in N(i)} feat[s]*dinv[s]  +  feat[i]*dinv[i]^2
template<int D, int LOGD>
__global__ void __launch_bounds__(256) k_pull(const int* __restrict__ rowstart,
                                              const int* __restrict__ csr_src,
                                              const float* __restrict__ dinv,
                                              const float* __restrict__ feat,
                                              float* __restrict__ out, int n) {
    constexpr int NV4 = D / 4;          // float4s per row
    constexpr int LOGNV4 = LOGD - 2;
    constexpr int EPI = 64 >> LOGNV4;   // edges in flight per wave
    int wid = (blockIdx.x * blockDim.x + threadIdx.x) >> 6;
    if (wid >= n) return;
    int lane = threadIdx.x & 63;
    int f4 = lane & (NV4 - 1);
    int j = lane >> LOGNV4;
    int beg = rowstart[wid], end = rowstart[wid + 1];
    float dd = dinv[wid];
    const float4* feat4 = (const float4*)feat;
    float4 acc = make_float4(0.f, 0.f, 0.f, 0.f);
    for (int k = beg + j; k < end; k += EPI) {
        int s = csr_src[k];
        float w = dinv[s];
        float4 v = feat4[(size_t)s * NV4 + f4];
        acc.x += v.x * w; acc.y += v.y * w; acc.z += v.z * w; acc.w += v.w * w;
    }
    for (int off = NV4; off < 64; off <<= 1) {
        acc.x += __shfl_xor(acc.x, off);
        acc.y += __shfl_xor(acc.y, off);
        acc.z += __shfl_xor(acc.z, off);
        acc.w += __shfl_xor(acc.w, off);
    }
    if (lane < NV4) {
        float4 sv = feat4[(size_t)wid * NV4 + lane];
        float ss = dd * dd;
        float4 o;
        o.x = acc.x * dd + sv.x * ss;
        o.y = acc.y * dd + sv.y * ss;
        o.z = acc.z * dd + sv.z * ss;
        o.w = acc.w * dd + sv.w * ss;
        ((float4*)out)[(size_t)wid * NV4 + lane] = o;
    }
}

// D=1 pull with fused bias + sigmoid (final layer)
__global__ void __launch_bounds__(256) k_pull1_sig(const int* __restrict__ rowstart,
                                                   const int* __restrict__ csr_src,
                                                   const float* __restrict__ dinv,
                                                   const float* __restrict__ t,
                                                   const float* __restrict__ b3,
                                                   float* __restrict__ out, int n) {
    int wid = (blockIdx.x * blockDim.x + threadIdx.x) >> 6;
    if (wid >= n) return;
    int lane = threadIdx.x & 63;
    int beg = rowstart[wid], end = rowstart[wid + 1];
    float dd = dinv[wid];
    float acc = 0.f;
    for (int k = beg + lane; k < end; k += 64) {
        int s = csr_src[k];
        acc += t[s] * dinv[s];
    }
    for (int off = 1; off < 64; off <<= 1) acc += __shfl_xor(acc, off);
    if (lane == 0) {
        float v = acc * dd + t[wid] * dd * dd + b3[0];
        out[wid] = 1.0f / (1.0f + expf(-v));
    }
}

// ---------------- dense layers ----------------

template<int IN, int OUT, bool RELU>
__global__ void __launch_bounds__(256) k_dense(const float* __restrict__ agg,
                                               const float* __restrict__ W,
                                               const float* __restrict__ b,
                                               float* __restrict__ out, int n) {
    __shared__ float sW[IN * OUT];
    __shared__ float sb[OUT];
    for (int i = threadIdx.x; i < IN * OUT; i += blockDim.x) sW[i] = W[i];
    for (int i = threadIdx.x; i < OUT; i += blockDim.x) sb[i] = b[i];
    __syncthreads();
    int node = blockIdx.x * blockDim.x + threadIdx.x;
    if (node >= n) return;
    float in[IN];
#pragma unroll
    for (int k = 0; k < IN; k++) in[k] = agg[(size_t)node * IN + k];
#pragma unroll
    for (int j = 0; j < OUT; j++) {
        float acc = sb[j];
#pragma unroll
        for (int k = 0; k < IN; k++) acc += in[k] * sW[k * OUT + j];
        out[(size_t)node * OUT + j] = RELU ? fmaxf(acc, 0.0f) : acc;
    }
}

__global__ void __launch_bounds__(256) k_dot64(const float* __restrict__ h,
                                               const float* __restrict__ W,
                                               float* __restrict__ out, int n) {
    __shared__ float sW[64];
    if (threadIdx.x < 64) sW[threadIdx.x] = W[threadIdx.x];
    __syncthreads();
    int i = blockIdx.x * blockDim.x + threadIdx.x;
    if (i >= n) return;
    const float4* row = (const float4*)(h + (size_t)i * 64);
    float acc = 0.0f;
#pragma unroll
    for (int k = 0; k < 16; k++) {
        float4 v = row[k];
        acc += v.x * sW[4 * k + 0] + v.y * sW[4 * k + 1] + v.z * sW[4 * k + 2] + v.w * sW[4 * k + 3];
    }
    out[i] = acc;
}

// ---------------- launch ----------------

static inline int cdiv(int a, int b) { return (a + b - 1) / b; }

extern "C" void kernel_launch(void* const* d_in, const int* in_sizes, int n_in,
                              void* d_out, int out_size, void* d_ws, size_t ws_size,
                              hipStream_t stream) {
    const float* x  = (const float*)d_in[0];
    const int*   ei = (const int*)d_in[1];
    const float* W1 = (const float*)d_in[2];
    const float* b1 = (const float*)d_in[3];
    const float* W2 = (const float*)d_in[4];
    const float* b2 = (const float*)d_in[5];
    const float* W3 = (const float*)d_in[6];
    const float* b3 = (const float*)d_in[7];

    const int n = in_sizes[0] / 16;
    const int e = in_sizes[1] / 2;
    const int* src = ei;
    const int* dst = ei + e;

    // workspace layout (4-byte elems, regions padded to 16 elems)
    auto rup = [](size_t v) { return (v + 15) & ~(size_t)15; };
    char* wp = (char*)d_ws;
    auto alloc = [&](size_t elems) { void* p = wp; wp += rup(elems) * 4; return p; };
    float* dinv     = (float*)alloc(n);
    int*   cnt      = (int*)  alloc(n);
    int*   rowstart = (int*)  alloc(n + 1);
    int*   cursor   = (int*)  alloc(n);
    int*   partial  = (int*)  alloc(1024);
    int*   csr_src  = (int*)  alloc(e);
    float* bufA     = (float*)alloc((size_t)32 * n);
    float* bufB     = (float*)alloc((size_t)64 * n);

    float* out = (float*)d_out;
    const int B = 256;

    // ---- CSR build ----
    hipMemsetAsync(cnt, 0, (size_t)n * 4, stream);
    k_hist<<<cdiv(e, B), B, 0, stream>>>(dst, cnt, e);
    k_dinv<<<cdiv(n, B), B, 0, stream>>>(cnt, dinv, n);
    int G1 = cdiv(n, SB);
    k_scan1<<<G1, SB, 0, stream>>>(cnt, partial, n);
    k_scanp<<<1, 1024, 0, stream>>>(partial, G1);
    k_scan2<<<G1, SB, 0, stream>>>(cnt, partial, rowstart, cursor, n, e);
    k_scatter<<<cdiv(e, B), B, 0, stream>>>(src, dst, cursor, csr_src, e);

    const int pullGrid = cdiv(n * 64, B);

    // ---- Layer 1: agg = A_hat @ x (16), h1 = relu(agg @ W1 + b1) (32)
    k_pull<16, 4><<<pullGrid, B, 0, stream>>>(rowstart, csr_src, dinv, x, bufA, n);
    k_dense<16, 32, true><<<cdiv(n, B), B, 0, stream>>>(bufA, W1, b1, bufB, n);

    // ---- Layer 2: agg = A_hat @ h1 (32), h2 = relu(agg @ W2 + b2) (64)
    k_pull<32, 5><<<pullGrid, B, 0, stream>>>(rowstart, csr_src, dinv, bufB, bufA, n);
    k_dense<32, 64, true><<<cdiv(n, B), B, 0, stream>>>(bufA, W2, b2, bufB, n);

    // ---- Layer 3: t = h2 @ W3 (1), out = sigmoid(A_hat @ t + b3)
    k_dot64<<<cdiv(n, B), B, 0, stream>>>(bufB, W3, bufA, n);  // t -> bufA
    k_pull1_sig<<<pullGrid, B, 0, stream>>>(rowstart, csr_src, dinv, bufA, b3, out, n);
}